// Round 1
// baseline (768.361 us; speedup 1.0000x reference)
//
#include <hip/hip_runtime.h>

#define NN   4096
#define DD   128
#define RR   8
#define OUTD 128
#define BB   4096

typedef unsigned short ushort_t;
typedef __attribute__((ext_vector_type(8))) short short8;
typedef __attribute__((ext_vector_type(4))) float floatx4;

__device__ __forceinline__ ushort_t f2bf(float f) {
  union { float f; unsigned int u; } v; v.f = f;
  unsigned int u = v.u;
  return (ushort_t)((u + 0x7fffu + ((u >> 16) & 1u)) >> 16);  // RNE
}

__device__ __forceinline__ short8 pack8(float4 a, float4 b) {
  short8 r;
  r[0] = (short)f2bf(a.x); r[1] = (short)f2bf(a.y);
  r[2] = (short)f2bf(a.z); r[3] = (short)f2bf(a.w);
  r[4] = (short)f2bf(b.x); r[5] = (short)f2bf(b.y);
  r[6] = (short)f2bf(b.z); r[7] = (short)f2bf(b.w);
  return r;
}

// ---------------------------------------------------------------------------
// Kernel A: Wt[r][o][m] = bf16( sum_d emb[m][d] * rk[r][d][o] )   (transposed)
// grid (64, 8), block 256. fp32 compute, LDS tiled.
// ---------------------------------------------------------------------------
__global__ __launch_bounds__(256) void compute_wt(const float* __restrict__ emb,
                                                  const float* __restrict__ rk,
                                                  ushort_t* __restrict__ Wt) {
  __shared__ float e_s[64][132];   // pad 132: stride%32==4 -> 2-way (free)
  __shared__ float k_s[128][36];   // pad 36
  const int r  = blockIdx.y;
  const int m0 = blockIdx.x * 64;
  const int t  = threadIdx.x;
  {
    const int row = t >> 2, q = t & 3;
    const float* src = emb + (size_t)(m0 + row) * DD;
    #pragma unroll
    for (int j = 0; j < 8; ++j) {
      const int c = q + 4 * j;
      *(float4*)&e_s[row][c * 4] = *(const float4*)(src + c * 4);
    }
  }
  const int m_l = t >> 2, ob = (t & 3) * 8;
  const float* rkr = rk + (size_t)r * DD * OUTD;
  #pragma unroll 1
  for (int oc = 0; oc < 4; ++oc) {
    __syncthreads();
    {
      const int d = t >> 1, h = (t & 1) * 4;
      #pragma unroll
      for (int j = 0; j < 4; ++j) {
        const int c = h + j;
        *(float4*)&k_s[d][c * 4] = *(const float4*)(rkr + d * OUTD + oc * 32 + c * 4);
      }
    }
    __syncthreads();
    float acc[8] = {0, 0, 0, 0, 0, 0, 0, 0};
    #pragma unroll 4
    for (int d = 0; d < DD; ++d) {
      const float e  = e_s[m_l][d];
      const float4 w0 = *(const float4*)&k_s[d][ob];
      const float4 w1 = *(const float4*)&k_s[d][ob + 4];
      acc[0] += e * w0.x; acc[1] += e * w0.y; acc[2] += e * w0.z; acc[3] += e * w0.w;
      acc[4] += e * w1.x; acc[5] += e * w1.y; acc[6] += e * w1.z; acc[7] += e * w1.w;
    }
    ushort_t* dst = Wt + ((size_t)r * OUTD + oc * 32 + ob) * NN + m0 + m_l;
    #pragma unroll
    for (int j = 0; j < 8; ++j) dst[(size_t)j * NN] = f2bf(acc[j]);
  }
}

// ---------------------------------------------------------------------------
// Kernel B: Z[n][o] += adj[r][n0+..][khalf+..] @ Wt[r]   (bf16 MFMA, split-K)
// grid (64, 16): x = n-tile (64 rows), y: r = y>>1, K-half = (y&1)*2048.
// block 256 = 4 waves; tile 64x128, BK=64. XOR-swizzled LDS chunks (16B).
// ---------------------------------------------------------------------------
__global__ __launch_bounds__(256) void rgcn_main(const float* __restrict__ adj,
                                                 const ushort_t* __restrict__ Wt,
                                                 float* __restrict__ Z) {
  __shared__ short8 A8[512];    // 64 rows  x 8 chunks (swizzled), 8 KB
  __shared__ short8 B8[1024];   // 128 o-rows x 8 chunks (swizzled), 16 KB
  const int r     = blockIdx.y >> 1;
  const int khalf = (blockIdx.y & 1) * 2048;
  const int n0    = blockIdx.x * 64;
  const int t = threadIdx.x;
  const int lane = t & 63, wave = t >> 6;
  const int wm = wave >> 1, wn = wave & 1;
  const int l15 = lane & 15, l4 = lane >> 4;
  const float*    adjr = adj + (size_t)r * NN * NN + (size_t)n0 * NN;
  const ushort_t* wtr  = Wt + (size_t)r * OUTD * NN;

  floatx4 acc[2][4] = {};

  const int arow = t >> 2, aq = t & 3;
  const int rl = arow & 7;

  for (int k0 = khalf; k0 < khalf + 2048; k0 += 64) {
    // --- A: 64x64 fp32 -> bf16, global->VGPR->cvt->LDS (swizzled) ---
    const float4* asrc = (const float4*)(adjr + (size_t)arow * NN + k0 + aq * 16);
    float4 a0 = asrc[0], a1 = asrc[1], a2 = asrc[2], a3 = asrc[3];
    // --- B: 128x64 bf16 via async 16B global_load_lds, swizzle on gaddr ---
    #pragma unroll
    for (int it = 0; it < 4; ++it) {
      const int s = wave * 256 + it * 64 + lane;
      const int o = s >> 3, kc = s & 7;
      const int gkc = kc ^ (o & 7);
      const ushort_t* gp = wtr + (size_t)o * NN + k0 + gkc * 8;
      __builtin_amdgcn_global_load_lds(
          (const __attribute__((address_space(1))) void*)gp,
          (__attribute__((address_space(3))) void*)&B8[wave * 256 + it * 64],
          16, 0, 0);
    }
    A8[arow * 8 + ((2 * aq) ^ rl)]     = pack8(a0, a1);
    A8[arow * 8 + ((2 * aq + 1) ^ rl)] = pack8(a2, a3);
    __syncthreads();
    #pragma unroll
    for (int kk = 0; kk < 2; ++kk) {
      short8 af[2], bf[4];
      #pragma unroll
      for (int ti = 0; ti < 2; ++ti) {
        const int row = wm * 32 + ti * 16 + l15;
        const int lc  = kk * 4 + l4;
        af[ti] = A8[row * 8 + (lc ^ (row & 7))];
      }
      #pragma unroll
      for (int tj = 0; tj < 4; ++tj) {
        const int orow = wn * 64 + tj * 16 + l15;
        const int lc   = kk * 4 + l4;
        bf[tj] = B8[orow * 8 + (lc ^ (orow & 7))];
      }
      #pragma unroll
      for (int ti = 0; ti < 2; ++ti)
        #pragma unroll
        for (int tj = 0; tj < 4; ++tj)
          acc[ti][tj] = __builtin_amdgcn_mfma_f32_16x16x32_bf16(af[ti], bf[tj],
                                                                acc[ti][tj], 0, 0, 0);
    }
    __syncthreads();
  }
  // --- epilogue: fp32 atomic accumulate into Z ---
  #pragma unroll
  for (int ti = 0; ti < 2; ++ti)
    #pragma unroll
    for (int tj = 0; tj < 4; ++tj)
      #pragma unroll
      for (int j = 0; j < 4; ++j) {
        const int nrow = n0 + wm * 32 + ti * 16 + l4 * 4 + j;
        const int ocol = wn * 64 + tj * 16 + l15;
        atomicAdd(Z + (size_t)nrow * OUTD + ocol, acc[ti][tj][j]);
      }
}

// ---------------------------------------------------------------------------
// Kernel C: out[branch][b][o] = e[b]@self_kernel + Z[idx[b]][o]
// grid 128: branch = x>>6, row tile = (x&63)*64. block 256.
// ---------------------------------------------------------------------------
__global__ __launch_bounds__(256) void epilogue_k(const float* __restrict__ he,
                                                  const float* __restrict__ te,
                                                  const int* __restrict__ hidx,
                                                  const int* __restrict__ tidx,
                                                  const float* __restrict__ sk,
                                                  const float* __restrict__ Z,
                                                  float* __restrict__ out) {
  __shared__ float e_s[64][132];
  __shared__ float k_s[128][36];
  const int bx = blockIdx.x;
  const int branch = bx >> 6;
  const int row0 = (bx & 63) * 64;
  const float* e  = branch ? te : he;
  const int* idx  = branch ? tidx : hidx;
  float* ob = out + (size_t)branch * BB * OUTD;
  const int t = threadIdx.x;
  {
    const int row = t >> 2, q = t & 3;
    const float* src = e + (size_t)(row0 + row) * DD;
    #pragma unroll
    for (int j = 0; j < 8; ++j) {
      const int c = q + 4 * j;
      *(float4*)&e_s[row][c * 4] = *(const float4*)(src + c * 4);
    }
  }
  const int m_l = t >> 2, obk = (t & 3) * 8;
  const int zi = idx[row0 + m_l];
  const float* zrow = Z + (size_t)zi * OUTD;
  #pragma unroll 1
  for (int oc = 0; oc < 4; ++oc) {
    __syncthreads();
    {
      const int d = t >> 1, h = (t & 1) * 4;
      #pragma unroll
      for (int j = 0; j < 4; ++j) {
        const int c = h + j;
        *(float4*)&k_s[d][c * 4] = *(const float4*)(sk + d * OUTD + oc * 32 + c * 4);
      }
    }
    __syncthreads();
    float acc[8] = {0, 0, 0, 0, 0, 0, 0, 0};
    #pragma unroll 4
    for (int d = 0; d < DD; ++d) {
      const float ev = e_s[m_l][d];
      const float4 w0 = *(const float4*)&k_s[d][obk];
      const float4 w1 = *(const float4*)&k_s[d][obk + 4];
      acc[0] += ev * w0.x; acc[1] += ev * w0.y; acc[2] += ev * w0.z; acc[3] += ev * w0.w;
      acc[4] += ev * w1.x; acc[5] += ev * w1.y; acc[6] += ev * w1.z; acc[7] += ev * w1.w;
    }
    const float4 z0 = *(const float4*)(zrow + oc * 32 + obk);
    const float4 z1 = *(const float4*)(zrow + oc * 32 + obk + 4);
    float4 o0, o1;
    o0.x = acc[0] + z0.x; o0.y = acc[1] + z0.y; o0.z = acc[2] + z0.z; o0.w = acc[3] + z0.w;
    o1.x = acc[4] + z1.x; o1.y = acc[5] + z1.y; o1.z = acc[6] + z1.z; o1.w = acc[7] + z1.w;
    *(float4*)&ob[(size_t)(row0 + m_l) * OUTD + oc * 32 + obk]     = o0;
    *(float4*)&ob[(size_t)(row0 + m_l) * OUTD + oc * 32 + obk + 4] = o1;
  }
}

extern "C" void kernel_launch(void* const* d_in, const int* in_sizes, int n_in,
                              void* d_out, int out_size, void* d_ws, size_t ws_size,
                              hipStream_t stream) {
  const float* emb  = (const float*)d_in[0];
  const int*   hidx = (const int*)  d_in[1];
  const float* he   = (const float*)d_in[2];
  const int*   tidx = (const int*)  d_in[3];
  const float* te   = (const float*)d_in[4];
  const float* adj  = (const float*)d_in[5];
  const float* rk   = (const float*)d_in[6];
  const float* sk   = (const float*)d_in[7];
  float* out = (float*)d_out;

  // ws layout: [0, 8MB) Wt bf16 (R*OUT*N), [8MB, 10MB) Z fp32 (N*OUT)
  ushort_t* Wt = (ushort_t*)d_ws;
  float*    Z  = (float*)((char*)d_ws + (size_t)RR * OUTD * NN * sizeof(ushort_t));

  hipMemsetAsync(Z, 0, (size_t)NN * OUTD * sizeof(float), stream);
  compute_wt<<<dim3(64, 8), 256, 0, stream>>>(emb, rk, Wt);
  rgcn_main<<<dim3(64, 16), 256, 0, stream>>>(adj, Wt, Z);
  epilogue_k<<<dim3(128), 256, 0, stream>>>(he, te, hidx, tidx, sk, Z, out);
}

// Round 2
// 756.198 us; speedup vs baseline: 1.0161x; 1.0161x over previous
//
#include <hip/hip_runtime.h>

#define NN   4096
#define DD   128
#define RR   8
#define OUTD 128
#define BB   4096

typedef unsigned short ushort_t;
typedef __attribute__((ext_vector_type(8))) short short8;
typedef __attribute__((ext_vector_type(4))) float floatx4;

__device__ __forceinline__ ushort_t f2bf(float f) {
  union { float f; unsigned int u; } v; v.f = f;
  unsigned int u = v.u;
  return (ushort_t)((u + 0x7fffu + ((u >> 16) & 1u)) >> 16);  // RNE
}

// pack two fp32 -> two bf16 (round-half-up) in one dword via v_perm_b32
__device__ __forceinline__ unsigned int pk2(float x, float y) {
  union { float f; unsigned int u; } a, b;
  a.f = x; b.f = y;
  const unsigned int ua = a.u + 0x8000u;
  const unsigned int ub = b.u + 0x8000u;
  // result.b0 = ua.b2, b1 = ua.b3, b2 = ub.b2, b3 = ub.b3
  return __builtin_amdgcn_perm(ub, ua, 0x07060302u);
}

__device__ __forceinline__ short8 pack8(float4 a, float4 b) {
  union { unsigned int u[4]; short8 s; } r;
  r.u[0] = pk2(a.x, a.y); r.u[1] = pk2(a.z, a.w);
  r.u[2] = pk2(b.x, b.y); r.u[3] = pk2(b.z, b.w);
  return r.s;
}

// ---------------------------------------------------------------------------
// Kernel A: Wt[r][o][m] = bf16( sum_d emb[m][d] * rk[r][d][o] )   (transposed)
// grid (64, 8), block 256. fp32 compute, LDS tiled.
// ---------------------------------------------------------------------------
__global__ __launch_bounds__(256) void compute_wt(const float* __restrict__ emb,
                                                  const float* __restrict__ rk,
                                                  ushort_t* __restrict__ Wt) {
  __shared__ float e_s[64][132];
  __shared__ float k_s[128][36];
  const int r  = blockIdx.y;
  const int m0 = blockIdx.x * 64;
  const int t  = threadIdx.x;
  {
    const int row = t >> 2, q = t & 3;
    const float* src = emb + (size_t)(m0 + row) * DD;
    #pragma unroll
    for (int j = 0; j < 8; ++j) {
      const int c = q + 4 * j;
      *(float4*)&e_s[row][c * 4] = *(const float4*)(src + c * 4);
    }
  }
  const int m_l = t >> 2, ob = (t & 3) * 8;
  const float* rkr = rk + (size_t)r * DD * OUTD;
  #pragma unroll 1
  for (int oc = 0; oc < 4; ++oc) {
    __syncthreads();
    {
      const int d = t >> 1, h = (t & 1) * 4;
      #pragma unroll
      for (int j = 0; j < 4; ++j) {
        const int c = h + j;
        *(float4*)&k_s[d][c * 4] = *(const float4*)(rkr + d * OUTD + oc * 32 + c * 4);
      }
    }
    __syncthreads();
    float acc[8] = {0, 0, 0, 0, 0, 0, 0, 0};
    #pragma unroll 4
    for (int d = 0; d < DD; ++d) {
      const float e  = e_s[m_l][d];
      const float4 w0 = *(const float4*)&k_s[d][ob];
      const float4 w1 = *(const float4*)&k_s[d][ob + 4];
      acc[0] += e * w0.x; acc[1] += e * w0.y; acc[2] += e * w0.z; acc[3] += e * w0.w;
      acc[4] += e * w1.x; acc[5] += e * w1.y; acc[6] += e * w1.z; acc[7] += e * w1.w;
    }
    ushort_t* dst = Wt + ((size_t)r * OUTD + oc * 32 + ob) * NN + m0 + m_l;
    #pragma unroll
    for (int j = 0; j < 8; ++j) dst[(size_t)j * NN] = f2bf(acc[j]);
  }
}

// ---------------------------------------------------------------------------
// Kernel B: Z[n][o] += adj[r][n0+..][khalf+..] @ Wt[r]   (bf16 MFMA, split-K)
// grid (64, 16): x = n-tile (64 rows), y: r = y>>1, K-half = (y&1)*2048.
// block 256 = 4 waves; tile 64x128, BK=128. XOR-swizzled 16B LDS chunks.
// ---------------------------------------------------------------------------
__global__ __launch_bounds__(256) void rgcn_main(const float* __restrict__ adj,
                                                 const ushort_t* __restrict__ Wt,
                                                 float* __restrict__ Z) {
  __shared__ short8 A8[1024];   // 64 rows  x 16 chunks (swizzled), 16 KB
  __shared__ short8 B8[2048];   // 128 rows x 16 chunks (swizzled), 32 KB
  const int r     = blockIdx.y >> 1;
  const int khalf = (blockIdx.y & 1) * 2048;
  const int n0    = blockIdx.x * 64;
  const int t = threadIdx.x;
  const int lane = t & 63, wave = t >> 6;
  const int wm = wave >> 1, wn = wave & 1;
  const int l15 = lane & 15, l4 = lane >> 4;   // l4 in 0..3
  const float*    adjr = adj + (size_t)r * NN * NN + (size_t)n0 * NN;
  const ushort_t* wtr  = Wt + (size_t)r * OUTD * NN;

  floatx4 acc[2][4] = {};

  const int arow = t >> 2, aq = t & 3;   // 64 rows x 4 quarters of 128B

  for (int k0 = khalf; k0 < khalf + 2048; k0 += 128) {
    // --- A: 64x128 fp32, global->VGPR (contiguous 128B per thread) ---
    const float4* asrc = (const float4*)(adjr + (size_t)arow * NN + k0) + aq * 8;
    float4 av[8];
    #pragma unroll
    for (int j = 0; j < 8; ++j) av[j] = asrc[j];
    // --- B: 128x128 bf16 via async 16B global_load_lds, swizzle on gaddr ---
    #pragma unroll
    for (int it = 0; it < 8; ++it) {
      const int s = wave * 512 + it * 64 + lane;
      const int o = s >> 4, kc = s & 15;
      const int gkc = kc ^ (o & 15);
      const ushort_t* gp = wtr + (size_t)o * NN + k0 + gkc * 8;
      __builtin_amdgcn_global_load_lds(
          (const __attribute__((address_space(1))) void*)gp,
          (__attribute__((address_space(3))) void*)&B8[wave * 512 + it * 64],
          16, 0, 0);
    }
    // --- A: cvt fp32->bf16 (v_perm pack) -> LDS (swizzled) ---
    #pragma unroll
    for (int j = 0; j < 4; ++j) {
      const int ck = aq * 4 + j;
      A8[arow * 16 + (ck ^ (arow & 15))] = pack8(av[2 * j], av[2 * j + 1]);
    }
    __syncthreads();
    #pragma unroll
    for (int kk = 0; kk < 4; ++kk) {
      short8 af[2], bf[4];
      #pragma unroll
      for (int ti = 0; ti < 2; ++ti) {
        const int row = wm * 32 + ti * 16 + l15;
        af[ti] = A8[row * 16 + ((kk * 4 + l4) ^ (row & 15))];
      }
      #pragma unroll
      for (int tj = 0; tj < 4; ++tj) {
        const int orow = wn * 64 + tj * 16 + l15;
        bf[tj] = B8[orow * 16 + ((kk * 4 + l4) ^ (orow & 15))];
      }
      #pragma unroll
      for (int ti = 0; ti < 2; ++ti)
        #pragma unroll
        for (int tj = 0; tj < 4; ++tj)
          acc[ti][tj] = __builtin_amdgcn_mfma_f32_16x16x32_bf16(af[ti], bf[tj],
                                                                acc[ti][tj], 0, 0, 0);
    }
    __syncthreads();
  }
  // --- epilogue: fp32 atomic accumulate into Z ---
  #pragma unroll
  for (int ti = 0; ti < 2; ++ti)
    #pragma unroll
    for (int tj = 0; tj < 4; ++tj)
      #pragma unroll
      for (int j = 0; j < 4; ++j) {
        const int nrow = n0 + wm * 32 + ti * 16 + l4 * 4 + j;
        const int ocol = wn * 64 + tj * 16 + l15;
        atomicAdd(Z + (size_t)nrow * OUTD + ocol, acc[ti][tj][j]);
      }
}

// ---------------------------------------------------------------------------
// Kernel C: out[branch][b][o] = e[b]@self_kernel + Z[idx[b]][o]
// grid 128: branch = x>>6, row tile = (x&63)*64. block 256.
// ---------------------------------------------------------------------------
__global__ __launch_bounds__(256) void epilogue_k(const float* __restrict__ he,
                                                  const float* __restrict__ te,
                                                  const int* __restrict__ hidx,
                                                  const int* __restrict__ tidx,
                                                  const float* __restrict__ sk,
                                                  const float* __restrict__ Z,
                                                  float* __restrict__ out) {
  __shared__ float e_s[64][132];
  __shared__ float k_s[128][36];
  const int bx = blockIdx.x;
  const int branch = bx >> 6;
  const int row0 = (bx & 63) * 64;
  const float* e  = branch ? te : he;
  const int* idx  = branch ? tidx : hidx;
  float* ob = out + (size_t)branch * BB * OUTD;
  const int t = threadIdx.x;
  {
    const int row = t >> 2, q = t & 3;
    const float* src = e + (size_t)(row0 + row) * DD;
    #pragma unroll
    for (int j = 0; j < 8; ++j) {
      const int c = q + 4 * j;
      *(float4*)&e_s[row][c * 4] = *(const float4*)(src + c * 4);
    }
  }
  const int m_l = t >> 2, obk = (t & 3) * 8;
  const int zi = idx[row0 + m_l];
  const float* zrow = Z + (size_t)zi * OUTD;
  #pragma unroll 1
  for (int oc = 0; oc < 4; ++oc) {
    __syncthreads();
    {
      const int d = t >> 1, h = (t & 1) * 4;
      #pragma unroll
      for (int j = 0; j < 4; ++j) {
        const int c = h + j;
        *(float4*)&k_s[d][c * 4] = *(const float4*)(sk + d * OUTD + oc * 32 + c * 4);
      }
    }
    __syncthreads();
    float acc[8] = {0, 0, 0, 0, 0, 0, 0, 0};
    #pragma unroll 4
    for (int d = 0; d < DD; ++d) {
      const float ev = e_s[m_l][d];
      const float4 w0 = *(const float4*)&k_s[d][obk];
      const float4 w1 = *(const float4*)&k_s[d][obk + 4];
      acc[0] += ev * w0.x; acc[1] += ev * w0.y; acc[2] += ev * w0.z; acc[3] += ev * w0.w;
      acc[4] += ev * w1.x; acc[5] += ev * w1.y; acc[6] += ev * w1.z; acc[7] += ev * w1.w;
    }
    const float4 z0 = *(const float4*)(zrow + oc * 32 + obk);
    const float4 z1 = *(const float4*)(zrow + oc * 32 + obk + 4);
    float4 o0, o1;
    o0.x = acc[0] + z0.x; o0.y = acc[1] + z0.y; o0.z = acc[2] + z0.z; o0.w = acc[3] + z0.w;
    o1.x = acc[4] + z1.x; o1.y = acc[5] + z1.y; o1.z = acc[6] + z1.z; o1.w = acc[7] + z1.w;
    *(float4*)&ob[(size_t)(row0 + m_l) * OUTD + oc * 32 + obk]     = o0;
    *(float4*)&ob[(size_t)(row0 + m_l) * OUTD + oc * 32 + obk + 4] = o1;
  }
}

extern "C" void kernel_launch(void* const* d_in, const int* in_sizes, int n_in,
                              void* d_out, int out_size, void* d_ws, size_t ws_size,
                              hipStream_t stream) {
  const float* emb  = (const float*)d_in[0];
  const int*   hidx = (const int*)  d_in[1];
  const float* he   = (const float*)d_in[2];
  const int*   tidx = (const int*)  d_in[3];
  const float* te   = (const float*)d_in[4];
  const float* adj  = (const float*)d_in[5];
  const float* rk   = (const float*)d_in[6];
  const float* sk   = (const float*)d_in[7];
  float* out = (float*)d_out;

  // ws layout: [0, 8MB) Wt bf16 (R*OUT*N), [8MB, 10MB) Z fp32 (N*OUT)
  ushort_t* Wt = (ushort_t*)d_ws;
  float*    Z  = (float*)((char*)d_ws + (size_t)RR * OUTD * NN * sizeof(ushort_t));

  hipMemsetAsync(Z, 0, (size_t)NN * OUTD * sizeof(float), stream);
  compute_wt<<<dim3(64, 8), 256, 0, stream>>>(emb, rk, Wt);
  rgcn_main<<<dim3(64, 16), 256, 0, stream>>>(adj, Wt, Z);
  epilogue_k<<<dim3(128), 256, 0, stream>>>(he, te, hidx, tidx, sk, Z, out);
}